// Round 7
// baseline (4709.472 us; speedup 1.0000x reference)
//
#include <hip/hip_runtime.h>
#include <stdint.h>

#define N      12288              // 96*128 descriptors
#define CH     512                // channels
#define TI     128                // rows per block (X-tile)
#define TJ     128                // cols per inner iteration (Y-tile)
#define KC     32                 // k-chunk
#define LDSTR  (TI + 4)           // 132 floats: keeps 16B alignment, breaks pow2 stride
#define NTILE  (N / TI)           // 96
#define NQ     4                  // j-range quarters per direction
#define JT_PER_Q (NTILE / NQ)     // 24

struct Top2 { float v0, v1; int i0, i1; };

// ---- module-scope device scratch: fixed addresses, graph-capture safe,
// ---- fully rewritten on every kernel_launch call (no cross-call state).
__device__ float g_invA[N];
__device__ float g_invB[N];
__device__ Top2  g_part[2][NQ][N];   // per-direction, per-quarter row top-2 partials
__device__ int   g_nn12[N];
__device__ float g_r12[N];
__device__ float g_sim0[N];
__device__ int   g_nn21[N];
__device__ float g_r21[N];

// insert candidate (v, idx) into running top-2; ties -> lower index first (lax.top_k)
__device__ __forceinline__ void t2_ins(float v, int idx,
                                       float& v0, int& i0, float& v1, int& i1) {
  bool beats0 = (v > v0) || (v == v0 && idx < i0);
  bool beats1 = (v > v1) || (v == v1 && idx < i1);
  if (beats0) { v1 = v0; i1 = i0; v0 = v; i0 = idx; }
  else if (beats1) { v1 = v; i1 = idx; }
}

// bf16 round-to-nearest-even, returned as the f32 it represents (expected
// outputs are bf16-quantized np values compared in f32 space)
__device__ __forceinline__ float bf16_quant(float f) {
  unsigned int u = __float_as_uint(f);
  unsigned int r = 0x7fffu + ((u >> 16) & 1u);
  unsigned int q = ((u + r) >> 16) << 16;
  return __uint_as_float(q);
}

// -------------------- kernel 1: inverse norms (fp32 inputs) --------------------
__global__ void norms_kernel(const float* __restrict__ A,
                             const float* __restrict__ B) {
  int i = blockIdx.x * 256 + threadIdx.x;
  if (i >= N) return;
  float sa = 0.f, sb = 0.f;
  for (int c = 0; c < CH; ++c) {
    float a = A[(size_t)c * N + i];
    float b = B[(size_t)c * N + i];
    sa += a * a;
    sb += b * b;
  }
  g_invA[i] = 1.0f / sqrtf(sa);
  g_invB[i] = 1.0f / sqrtf(sb);
}

// -------------------- kernel 2: GEMM strip + row top-2 over a j-quarter --------------------
// gridDim = (96, 8). by>>2 = dir (0: rows of sim, X=A,Y=B; 1: rows of sim.T, X=B,Y=A).
// by&3 = j-quarter (24 j-tiles each). Each block owns 128 X-rows; partial top-2 per
// quarter -> g_part, merged by kernel 3. No atomics, no d_ws.
__global__ __launch_bounds__(256)
void sim_top2_part_kernel(const float* __restrict__ A,
                          const float* __restrict__ B) {
  __shared__ float Xs[KC][LDSTR];
  __shared__ float Ys[KC][LDSTR];
  __shared__ Top2 rowTop[TI];

  const int dir = blockIdx.y >> 2;
  const int q   = blockIdx.y & 3;
  const float* X = dir ? B : A;
  const float* Y = dir ? A : B;
  const float* invX = dir ? g_invB : g_invA;
  const float* invY = dir ? g_invA : g_invB;

  const int i0 = blockIdx.x * TI;
  const int tid = threadIdx.x;
  const int tx = tid & 15;     // col group
  const int ty = tid >> 4;     // row group

  if (tid < TI) {
    rowTop[tid].v0 = -1e30f; rowTop[tid].v1 = -1e30f;
    rowTop[tid].i0 = 0x7fffffff; rowTop[tid].i1 = 0x7fffffff;
  }
  __syncthreads();

  float ia[8];
#pragma unroll
  for (int r = 0; r < 8; ++r) ia[r] = invX[i0 + ty * 8 + r];

  const int sk = tid >> 3;        // 0..31: k-row within chunk
  const int si = (tid & 7) * 16;  // 0..112: float start within tile row

  for (int jt = q * JT_PER_Q; jt < (q + 1) * JT_PER_Q; ++jt) {
    const int j0 = jt * TJ;
    float acc[8][8];
#pragma unroll
    for (int r = 0; r < 8; ++r)
#pragma unroll
      for (int c = 0; c < 8; ++c) acc[r][c] = 0.f;

    for (int kc = 0; kc < CH; kc += KC) {
      __syncthreads();
      const float* gx = X + (size_t)(kc + sk) * N + i0 + si;
      const float* gy = Y + (size_t)(kc + sk) * N + j0 + si;
      float4 x0 = *reinterpret_cast<const float4*>(gx);
      float4 x1 = *reinterpret_cast<const float4*>(gx + 4);
      float4 x2 = *reinterpret_cast<const float4*>(gx + 8);
      float4 x3 = *reinterpret_cast<const float4*>(gx + 12);
      float4 y0 = *reinterpret_cast<const float4*>(gy);
      float4 y1 = *reinterpret_cast<const float4*>(gy + 4);
      float4 y2 = *reinterpret_cast<const float4*>(gy + 8);
      float4 y3 = *reinterpret_cast<const float4*>(gy + 12);
      *reinterpret_cast<float4*>(&Xs[sk][si])      = x0;
      *reinterpret_cast<float4*>(&Xs[sk][si + 4])  = x1;
      *reinterpret_cast<float4*>(&Xs[sk][si + 8])  = x2;
      *reinterpret_cast<float4*>(&Xs[sk][si + 12]) = x3;
      *reinterpret_cast<float4*>(&Ys[sk][si])      = y0;
      *reinterpret_cast<float4*>(&Ys[sk][si + 4])  = y1;
      *reinterpret_cast<float4*>(&Ys[sk][si + 8])  = y2;
      *reinterpret_cast<float4*>(&Ys[sk][si + 12]) = y3;
      __syncthreads();
#pragma unroll 4
      for (int k = 0; k < KC; ++k) {
        float a[8] __attribute__((aligned(16)));
        float b[8] __attribute__((aligned(16)));
        *reinterpret_cast<float4*>(&a[0]) = *reinterpret_cast<const float4*>(&Xs[k][ty * 8]);
        *reinterpret_cast<float4*>(&a[4]) = *reinterpret_cast<const float4*>(&Xs[k][ty * 8 + 4]);
        *reinterpret_cast<float4*>(&b[0]) = *reinterpret_cast<const float4*>(&Ys[k][tx * 8]);
        *reinterpret_cast<float4*>(&b[4]) = *reinterpret_cast<const float4*>(&Ys[k][tx * 8 + 4]);
#pragma unroll
        for (int r = 0; r < 8; ++r)
#pragma unroll
          for (int c = 0; c < 8; ++c)
            acc[r][c] += a[r] * b[c];
      }
    }

    // scale raw dots by inverse norms -> true cosine sim; then row top-2
    float ib[8];
#pragma unroll
    for (int c = 0; c < 8; ++c) ib[c] = invY[j0 + tx * 8 + c];
#pragma unroll
    for (int r = 0; r < 8; ++r) {
      float s = ia[r];
      float v0 = -1e30f, v1 = -1e30f; int id0 = 0x7fffffff, id1 = 0x7fffffff;
#pragma unroll
      for (int c = 0; c < 8; ++c) {
        float v = acc[r][c] * (s * ib[c]);
        t2_ins(v, j0 + tx * 8 + c, v0, id0, v1, id1);
      }
      // reduce across the 16 tx lanes (xor masks < 16 stay in the tx group)
#pragma unroll
      for (int m = 1; m < 16; m <<= 1) {
        float ov0 = __shfl_xor(v0, m), ov1 = __shfl_xor(v1, m);
        int   oi0 = __shfl_xor(id0, m), oi1 = __shfl_xor(id1, m);
        t2_ins(ov0, oi0, v0, id0, v1, id1);
        t2_ins(ov1, oi1, v0, id0, v1, id1);
      }
      if (tx == 0) {  // unique owner (ty) per row -> no race
        Top2 t = rowTop[ty * 8 + r];
        t2_ins(v0, id0, t.v0, t.i0, t.v1, t.i1);
        t2_ins(v1, id1, t.v0, t.i0, t.v1, t.i1);
        rowTop[ty * 8 + r] = t;
      }
    }
  }

  __syncthreads();
  if (tid < TI) g_part[dir][q][i0 + tid] = rowTop[tid];
}

// -------------------- kernel 3: merge quarters -> nn / ratio / sim0 per direction --------------------
__global__ void merge_kernel() {
  int t = blockIdx.x * 256 + threadIdx.x;
  if (t >= 2 * N) return;
  int dir = t / N, i = t % N;
  float v0 = -1e30f, v1 = -1e30f; int id0 = 0x7fffffff, id1 = 0x7fffffff;
#pragma unroll
  for (int q = 0; q < NQ; ++q) {
    Top2 p = g_part[dir][q][i];
    t2_ins(p.v0, p.i0, v0, id0, v1, id1);
    t2_ins(p.v1, p.i1, v0, id0, v1, id1);
  }
  float d0 = 2.f - 2.f * v0, d1 = 2.f - 2.f * v1;
  float ratio = d0 / (d1 + 1e-8f);
  if (dir == 0) {
    g_nn12[i] = id0; g_r12[i] = ratio; g_sim0[i] = v0;
  } else {
    g_nn21[i] = id0; g_r21[i] = ratio;
  }
}

// -------------------- kernel 4: ratio test + mutual-NN mask, write FP32 outputs --------------------
// d_out is float32 (3*N): [masked_sim | nn12 | mask]. Expected values are
// bf16-quantized np outputs, so store bf16-rounded values for near-zero error.
__global__ void finalize_kernel(float* __restrict__ out) {
  int i = blockIdx.x * 256 + threadIdx.x;
  if (i >= N) return;
  int j = g_nn12[i];
  int jc = j < 0 ? 0 : (j >= N ? N - 1 : j);   // OOB guard
  bool mask = (g_nn21[jc] == i) && (g_r12[i] <= 0.95f) && (g_r21[jc] <= 0.95f);
  out[i]         = bf16_quant(mask ? g_sim0[i] : 0.f);
  out[N + i]     = bf16_quant((float)j);
  out[2 * N + i] = mask ? 1.f : 0.f;
}

extern "C" void kernel_launch(void* const* d_in, const int* in_sizes, int n_in,
                              void* d_out, int out_size, void* d_ws, size_t ws_size,
                              hipStream_t stream) {
  const float* A = (const float*)d_in[0];  // fp32, channel-major [CH][N]
  const float* B = (const float*)d_in[1];
  (void)d_ws; (void)ws_size;  // scratch lives in __device__ globals

  norms_kernel<<<dim3((N + 255) / 256), 256, 0, stream>>>(A, B);
  sim_top2_part_kernel<<<dim3(NTILE, 2 * NQ), 256, 0, stream>>>(A, B);
  merge_kernel<<<dim3((2 * N + 255) / 256), 256, 0, stream>>>();
  finalize_kernel<<<dim3((N + 255) / 256), 256, 0, stream>>>((float*)d_out);
}

// Round 8
// 2914.766 us; speedup vs baseline: 1.6157x; 1.6157x over previous
//
#include <hip/hip_runtime.h>
#include <stdint.h>

#define N      12288              // 96*128 descriptors
#define CH     512                // channels
#define TI     128                // rows per block (i-tile)
#define TJ     128                // cols per inner iteration (j-tile)
#define KC     32                 // k-chunk
#define LDSTR  (TI + 4)           // 132 floats: 16B-aligned rows, breaks pow2 stride
#define NTILE  (N / TI)           // 96
#define NS     8                  // j-slices (grid.y)
#define JT_PER_S (NTILE / NS)     // 12 j-tiles per slice

struct Top2 { float v0, v1; int i0, i1; };

// ---- module-scope device scratch: fixed addresses, graph-capture safe,
// ---- fully rewritten on every kernel_launch call.
__device__ float g_invA[N];
__device__ float g_invB[N];
__device__ Top2  g_rpart[NS][N];      // row top-2 partials per j-slice   (1.6 MB)
__device__ Top2  g_cpart[NTILE][N];   // col top-2 partials per i-tile   (18.9 MB)
__device__ int   g_nn12[N];
__device__ float g_r12[N];
__device__ float g_sim0[N];
__device__ int   g_nn21[N];
__device__ float g_r21[N];

// insert candidate (v, idx) into running top-2; ties -> lower index first (lax.top_k)
__device__ __forceinline__ void t2_ins(float v, int idx,
                                       float& v0, int& i0, float& v1, int& i1) {
  bool beats0 = (v > v0) || (v == v0 && idx < i0);
  bool beats1 = (v > v1) || (v == v1 && idx < i1);
  if (beats0) { v1 = v0; i1 = i0; v0 = v; i0 = idx; }
  else if (beats1) { v1 = v; i1 = idx; }
}

// bf16 RNE quantize, kept in f32 (expected outputs are bf16-quantized np values)
__device__ __forceinline__ float bf16_quant(float f) {
  unsigned int u = __float_as_uint(f);
  unsigned int r = 0x7fffu + ((u >> 16) & 1u);
  unsigned int q = ((u + r) >> 16) << 16;
  return __uint_as_float(q);
}

// -------------------- kernel 1: inverse norms --------------------
__global__ void norms_kernel(const float* __restrict__ A,
                             const float* __restrict__ B) {
  int i = blockIdx.x * 256 + threadIdx.x;
  if (i >= N) return;
  float sa = 0.f, sb = 0.f;
  for (int c = 0; c < CH; ++c) {
    float a = A[(size_t)c * N + i];
    float b = B[(size_t)c * N + i];
    sa += a * a;
    sb += b * b;
  }
  g_invA[i] = 1.0f / sqrtf(sa);
  g_invB[i] = 1.0f / sqrtf(sb);
}

// -------------------- kernel 2: single-pass GEMM + row AND col top-2 --------------------
// grid (96, 8): i-tile, j-slice (12 j-tiles each). Thread tile: 4x4 quadrants —
// rows {ty*4+r, 64+ty*4+r}, cols {tx*4+c, 64+tx*4+c} -> all LDS fragment reads
// are 16B-stride = 2-way bank aliasing (free on gfx950, m136).
__global__ __launch_bounds__(256)
void sim_top2_kernel(const float* __restrict__ A,
                     const float* __restrict__ B) {
  __shared__ float Xs[KC][LDSTR];
  __shared__ float Ys[KC][LDSTR];
  __shared__ Top2 rowTop[TI];
  __shared__ Top2 colWave[4][TJ];

  const int itile = blockIdx.x;
  const int slice = blockIdx.y;
  const int i0 = itile * TI;
  const int tid = threadIdx.x;
  const int tx = tid & 15;
  const int ty = tid >> 4;
  const int wave = tid >> 6;

  if (tid < TI) {
    rowTop[tid].v0 = -1e30f; rowTop[tid].v1 = -1e30f;
    rowTop[tid].i0 = 0x7fffffff; rowTop[tid].i1 = 0x7fffffff;
  }
  __syncthreads();

  // inverse norms for this thread's 8 rows (2 quadrants x 4)
  float ia[8];
#pragma unroll
  for (int u = 0; u < 8; ++u) {
    int row = (u < 4) ? (ty * 4 + u) : (64 + ty * 4 + (u - 4));
    ia[u] = g_invA[i0 + row];
  }

  const int sk = tid >> 3;        // 0..31: k-row within chunk
  const int si = (tid & 7) * 16;  // 0..112: float start within tile row

  for (int jt = slice * JT_PER_S; jt < (slice + 1) * JT_PER_S; ++jt) {
    const int j0 = jt * TJ;
    float acc[8][8];
#pragma unroll
    for (int u = 0; u < 8; ++u)
#pragma unroll
      for (int v = 0; v < 8; ++v) acc[u][v] = 0.f;

    for (int kc = 0; kc < CH; kc += KC) {
      __syncthreads();
      const float* gx = A + (size_t)(kc + sk) * N + i0 + si;
      const float* gy = B + (size_t)(kc + sk) * N + j0 + si;
      float4 x0 = *reinterpret_cast<const float4*>(gx);
      float4 x1 = *reinterpret_cast<const float4*>(gx + 4);
      float4 x2 = *reinterpret_cast<const float4*>(gx + 8);
      float4 x3 = *reinterpret_cast<const float4*>(gx + 12);
      float4 y0 = *reinterpret_cast<const float4*>(gy);
      float4 y1 = *reinterpret_cast<const float4*>(gy + 4);
      float4 y2 = *reinterpret_cast<const float4*>(gy + 8);
      float4 y3 = *reinterpret_cast<const float4*>(gy + 12);
      *reinterpret_cast<float4*>(&Xs[sk][si])      = x0;
      *reinterpret_cast<float4*>(&Xs[sk][si + 4])  = x1;
      *reinterpret_cast<float4*>(&Xs[sk][si + 8])  = x2;
      *reinterpret_cast<float4*>(&Xs[sk][si + 12]) = x3;
      *reinterpret_cast<float4*>(&Ys[sk][si])      = y0;
      *reinterpret_cast<float4*>(&Ys[sk][si + 4])  = y1;
      *reinterpret_cast<float4*>(&Ys[sk][si + 8])  = y2;
      *reinterpret_cast<float4*>(&Ys[sk][si + 12]) = y3;
      __syncthreads();
#pragma unroll 4
      for (int k = 0; k < KC; ++k) {
        float a[8] __attribute__((aligned(16)));
        float b[8] __attribute__((aligned(16)));
        *reinterpret_cast<float4*>(&a[0]) = *reinterpret_cast<const float4*>(&Xs[k][ty * 4]);
        *reinterpret_cast<float4*>(&a[4]) = *reinterpret_cast<const float4*>(&Xs[k][64 + ty * 4]);
        *reinterpret_cast<float4*>(&b[0]) = *reinterpret_cast<const float4*>(&Ys[k][tx * 4]);
        *reinterpret_cast<float4*>(&b[4]) = *reinterpret_cast<const float4*>(&Ys[k][64 + tx * 4]);
#pragma unroll
        for (int u = 0; u < 8; ++u)
#pragma unroll
          for (int v = 0; v < 8; ++v)
            acc[u][v] += a[u] * b[v];
      }
    }

    // scale by inverse norms -> cosine sim
    float ib[8];
#pragma unroll
    for (int v = 0; v < 8; ++v) {
      int col = (v < 4) ? (tx * 4 + v) : (64 + tx * 4 + (v - 4));
      ib[v] = g_invB[j0 + col];
    }
#pragma unroll
    for (int u = 0; u < 8; ++u) {
      float s = ia[u];
#pragma unroll
      for (int v = 0; v < 8; ++v) acc[u][v] *= s * ib[v];
    }

    // ---- row top-2 over this j-tile: reduce across tx (16-lane groups) ----
#pragma unroll
    for (int u = 0; u < 8; ++u) {
      float v0 = -1e30f, v1 = -1e30f; int id0 = 0x7fffffff, id1 = 0x7fffffff;
#pragma unroll
      for (int v = 0; v < 8; ++v) {
        int col = (v < 4) ? (tx * 4 + v) : (64 + tx * 4 + (v - 4));
        t2_ins(acc[u][v], j0 + col, v0, id0, v1, id1);
      }
#pragma unroll
      for (int m = 1; m < 16; m <<= 1) {
        float ov0 = __shfl_xor(v0, m), ov1 = __shfl_xor(v1, m);
        int   oi0 = __shfl_xor(id0, m), oi1 = __shfl_xor(id1, m);
        t2_ins(ov0, oi0, v0, id0, v1, id1);
        t2_ins(ov1, oi1, v0, id0, v1, id1);
      }
      if (tx == 0) {  // unique owner (ty,u) per row -> no race
        int rl = (u < 4) ? (ty * 4 + u) : (64 + ty * 4 + (u - 4));
        Top2 t = rowTop[rl];
        t2_ins(v0, id0, t.v0, t.i0, t.v1, t.i1);
        t2_ins(v1, id1, t.v0, t.i0, t.v1, t.i1);
        rowTop[rl] = t;
      }
    }

    // ---- col top-2 over this i-tile: reduce 8 local rows, then across ty ----
#pragma unroll
    for (int v = 0; v < 8; ++v) {
      float v0 = -1e30f, v1 = -1e30f; int id0 = 0x7fffffff, id1 = 0x7fffffff;
#pragma unroll
      for (int u = 0; u < 8; ++u) {
        int row = (u < 4) ? (ty * 4 + u) : (64 + ty * 4 + (u - 4));
        t2_ins(acc[u][v], i0 + row, v0, id0, v1, id1);
      }
#pragma unroll
      for (int m = 16; m < 64; m <<= 1) {   // reduce over 4 ty values in-wave
        float ov0 = __shfl_xor(v0, m), ov1 = __shfl_xor(v1, m);
        int   oi0 = __shfl_xor(id0, m), oi1 = __shfl_xor(id1, m);
        t2_ins(ov0, oi0, v0, id0, v1, id1);
        t2_ins(ov1, oi1, v0, id0, v1, id1);
      }
      if ((ty & 3) == 0) {
        int cl = (v < 4) ? (tx * 4 + v) : (64 + tx * 4 + (v - 4));
        Top2 t; t.v0 = v0; t.v1 = v1; t.i0 = id0; t.i1 = id1;
        colWave[wave][cl] = t;
      }
    }
    __syncthreads();
    if (tid < TJ) {
      Top2 t = colWave[0][tid];
#pragma unroll
      for (int w = 1; w < 4; ++w) {
        Top2 o = colWave[w][tid];
        t2_ins(o.v0, o.i0, t.v0, t.i0, t.v1, t.i1);
        t2_ins(o.v1, o.i1, t.v0, t.i0, t.v1, t.i1);
      }
      g_cpart[itile][j0 + tid] = t;
    }
  }

  __syncthreads();
  if (tid < TI) g_rpart[slice][i0 + tid] = rowTop[tid];
}

// -------------------- kernel 3: merge partials (rows over 8 slices, cols over 96 i-tiles) ----
__global__ void merge_kernel() {
  int i = blockIdx.x * 256 + threadIdx.x;
  if (i >= N) return;

  {
    float v0 = -1e30f, v1 = -1e30f; int id0 = 0x7fffffff, id1 = 0x7fffffff;
#pragma unroll
    for (int s = 0; s < NS; ++s) {
      Top2 p = g_rpart[s][i];
      t2_ins(p.v0, p.i0, v0, id0, v1, id1);
      t2_ins(p.v1, p.i1, v0, id0, v1, id1);
    }
    float d0 = 2.f - 2.f * v0, d1 = 2.f - 2.f * v1;
    g_nn12[i] = id0; g_r12[i] = d0 / (d1 + 1e-8f); g_sim0[i] = v0;
  }
  {
    float v0 = -1e30f, v1 = -1e30f; int id0 = 0x7fffffff, id1 = 0x7fffffff;
    for (int it = 0; it < NTILE; ++it) {
      Top2 p = g_cpart[it][i];
      t2_ins(p.v0, p.i0, v0, id0, v1, id1);
      t2_ins(p.v1, p.i1, v0, id0, v1, id1);
    }
    float d0 = 2.f - 2.f * v0, d1 = 2.f - 2.f * v1;
    g_nn21[i] = id0; g_r21[i] = d0 / (d1 + 1e-8f);
  }
}

// -------------------- kernel 4: mutual-NN + ratio mask, write FP32 outputs --------------------
__global__ void finalize_kernel(float* __restrict__ out) {
  int i = blockIdx.x * 256 + threadIdx.x;
  if (i >= N) return;
  int j = g_nn12[i];
  int jc = j < 0 ? 0 : (j >= N ? N - 1 : j);   // OOB guard
  bool mask = (g_nn21[jc] == i) && (g_r12[i] <= 0.95f) && (g_r21[jc] <= 0.95f);
  out[i]         = bf16_quant(mask ? g_sim0[i] : 0.f);
  out[N + i]     = bf16_quant((float)j);
  out[2 * N + i] = mask ? 1.f : 0.f;
}

extern "C" void kernel_launch(void* const* d_in, const int* in_sizes, int n_in,
                              void* d_out, int out_size, void* d_ws, size_t ws_size,
                              hipStream_t stream) {
  const float* A = (const float*)d_in[0];  // fp32, channel-major [CH][N]
  const float* B = (const float*)d_in[1];
  (void)d_ws; (void)ws_size;  // scratch lives in __device__ globals

  norms_kernel<<<dim3((N + 255) / 256), 256, 0, stream>>>(A, B);
  sim_top2_kernel<<<dim3(NTILE, NS), 256, 0, stream>>>(A, B);
  merge_kernel<<<dim3((N + 255) / 256), 256, 0, stream>>>();
  finalize_kernel<<<dim3((N + 255) / 256), 256, 0, stream>>>((float*)d_out);
}